// Round 4
// baseline (76.804 us; speedup 1.0000x reference)
//
#include <hip/hip_runtime.h>
#include <stdint.h>

#define NBINS 313
#define NBQ   320        // padded to a multiple of 8 for clean unroll
#define HW    65536      // 256*256
#define NPIX  (4 * HW)   // 262144
#define HALF  (NPIX / 2) // 131072

// Kernel 1: per-pixel NN weight + weighted L2, block partial sums -> d_ws
__global__ __launch_bounds__(256) void loss_main(
    const float* __restrict__ input, const float* __restrict__ target,
    const float* __restrict__ ab, const float* __restrict__ prior,
    float* __restrict__ partials)
{
    __shared__ float4 s_bins[NBQ];   // {gx, gy, 0.5*|g|^2 + 4, unused}
    __shared__ float  s_w[NBQ];
    const int tid = threadIdx.x;

    for (int i = tid; i < NBQ; i += 256) {
        float gx = 0.0f, gy = 0.0f, z = 1e30f, w = 0.0f;
        if (i < NBINS) {
            gx = ab[2 * i];
            gy = ab[2 * i + 1];
            z  = fmaf(0.5f * gx, gx, fmaf(0.5f * gy, gy, 4.0f));
            w  = prior[i];
        }
        s_bins[i] = make_float4(gx, gy, z, 0.0f);
        s_w[i] = w;
    }
    __syncthreads();

    // Two pixels per thread: p0 in first half, p1 in second half (coalesced)
    const int p0 = blockIdx.x * 256 + tid;
    const int p1 = p0 + HALF;

    // pixel p -> flat idx of channel0: (b*2)*HW + n = p + (p & ~(HW-1))
    const int i00 = p0 + (p0 & ~(HW - 1));
    const int i01 = i00 + HW;
    const int i10 = p1 + (p1 & ~(HW - 1));
    const int i11 = i10 + HW;

    const float tx0 = target[i00], ty0 = target[i01];
    const float tx1 = target[i10], ty1 = target[i11];
    const float ax0 = input[i00],  ay0 = input[i01];
    const float ax1 = input[i10],  ay1 = input[i11];

    const float dx0 = ax0 - tx0, dy0 = ay0 - ty0;
    const float dx1 = ax1 - tx1, dy1 = ay1 - ty1;
    const float d2_0 = dx0 * dx0 + dy0 * dy0;
    const float d2_1 = dx1 * dx1 + dy1 * dy1;

    // argmin of (0.5|g|^2 - g.t) via positive-float bit ordering with the
    // bin index packed into the CLEARED low 9 mantissa bits: ties -> smallest
    // q, matching jnp.argmin. f in [2.3, 6.5] so bits(f) is order-preserving;
    // clearing 9 low mantissa bits perturbs f by <= 2.4e-4 (only near-ties
    // can flip, harmless at loss scale).
    uint32_t u0 = 0xFFFFFFFFu, u1 = 0xFFFFFFFFu;
#pragma unroll 8
    for (int q = 0; q < NBQ; ++q) {
        const float4 bn = s_bins[q];
        const float f0 = fmaf(-bn.x, tx0, fmaf(-bn.y, ty0, bn.z));
        const float f1 = fmaf(-bn.x, tx1, fmaf(-bn.y, ty1, bn.z));
        const uint32_t v0 = (__float_as_uint(f0) & ~511u) | (uint32_t)q;
        const uint32_t v1 = (__float_as_uint(f1) & ~511u) | (uint32_t)q;
        u0 = v0 < u0 ? v0 : u0;
        u1 = v1 < u1 ? v1 : u1;
    }

    const float bw0 = s_w[u0 & 511u];
    const float bw1 = s_w[u1 & 511u];

    float sum = fmaf(d2_0, bw0, d2_1 * bw1);

    // wave (64) reduce, then cross-wave via LDS
    for (int off = 32; off > 0; off >>= 1)
        sum += __shfl_down(sum, off);

    __shared__ float s_part[4];
    if ((tid & 63) == 0) s_part[tid >> 6] = sum;
    __syncthreads();
    if (tid == 0)
        partials[blockIdx.x] = s_part[0] + s_part[1] + s_part[2] + s_part[3];
}

// Kernel 2: reduce 512 partials -> scalar loss (mean over batch: *0.25)
__global__ __launch_bounds__(64) void loss_reduce(
    const float* __restrict__ partials, float* __restrict__ out)
{
    const int tid = threadIdx.x;
    float s = 0.0f;
    for (int i = tid; i < 512; i += 64) s += partials[i];
    for (int off = 32; off > 0; off >>= 1)
        s += __shfl_down(s, off);
    if (tid == 0) out[0] = 0.25f * s;
}

extern "C" void kernel_launch(void* const* d_in, const int* in_sizes, int n_in,
                              void* d_out, int out_size, void* d_ws, size_t ws_size,
                              hipStream_t stream)
{
    const float* input  = (const float*)d_in[0];
    const float* target = (const float*)d_in[1];
    const float* ab     = (const float*)d_in[2];
    const float* prior  = (const float*)d_in[3];
    float* out      = (float*)d_out;
    float* partials = (float*)d_ws;

    loss_main<<<HALF / 256, 256, 0, stream>>>(input, target, ab, prior, partials);
    loss_reduce<<<1, 64, 0, stream>>>(partials, out);
}